// Round 17
// baseline (56.436 us; speedup 1.0000x reference)
//
#include <hip/hip_runtime.h>
#include <hip/hip_bf16.h>
#include <stdint.h>

// Problem constants
#define BATCH 8
#define SEQ   2048
#define DEMB  1024
#define HD    64
#define NROWS (BATCH * SEQ)   // 16384
#define NSPL  4               // KV split factor

typedef __attribute__((ext_vector_type(8))) short bf16x8;  // 8 bf16 in 4 VGPRs
typedef __attribute__((ext_vector_type(4))) short s16x4;   // 4 bf16 (8 B)
typedef __attribute__((ext_vector_type(4))) float f32x4;

// fp32 -> bf16 round-to-nearest-even (bit pattern as short)
__device__ inline short f2b(float f) {
    unsigned u = __builtin_bit_cast(unsigned, f);
    unsigned r = (u + 0x7fffu + ((u >> 16) & 1u)) >> 16;
    return (short)r;
}
// native cast path (compiler can fuse pairs into v_cvt_pk_bf16_f32)
__device__ inline short f2bn(float f) {
    __hip_bfloat16 h(f);
    return __builtin_bit_cast(short, h);
}

// async global->LDS, 16 B per lane; dest = lds_base (wave-uniform) + lane*16
__device__ inline void gload_lds16(const void* g, void* l) {
    auto gp = reinterpret_cast<const __attribute__((address_space(1))) void*>(
        reinterpret_cast<uintptr_t>(g));
    auto lp = reinterpret_cast<__attribute__((address_space(3))) void*>(
        reinterpret_cast<uintptr_t>(l));
    __builtin_amdgcn_global_load_lds(gp, lp, 16, 0, 0);
}

// ---------------------------------------------------------------------------
// Kernel 0: prep — Wt[n][d] = W(d,n) as bf16; bias[192] fp32 concat
// ---------------------------------------------------------------------------
__global__ void prep_kernel(const float* __restrict__ Wq, const float* __restrict__ bq,
                            const float* __restrict__ Wk, const float* __restrict__ bk,
                            const float* __restrict__ Wv, const float* __restrict__ bv,
                            short* __restrict__ Wt, float* __restrict__ bias) {
    int idx = blockIdx.x * blockDim.x + threadIdx.x;   // 0 .. 192*1024-1
    if (idx < 192 * 1024) {
        int n = idx >> 10;
        int d = idx & 1023;
        const float* W = (n < 64) ? Wq : (n < 128) ? Wk : Wv;
        int nn = n & 63;
        Wt[idx] = f2b(W[(size_t)d * 64 + nn]);
    }
    if (idx < 192) {
        const float* bb = (idx < 64) ? bq : (idx < 128) ? bk : bv;
        bias[idx] = bb[idx & 63];
    }
}

// ---------------------------------------------------------------------------
// Kernel 1: QKV projection — r15 N-split version (passing, unchanged).
//   BM=32, BN=96, grid 1024 (bid = c*512 + r), LDS 32KB -> 4 blocks/CU.
// ---------------------------------------------------------------------------
__global__ __launch_bounds__(256) void proj_kernel(const float* __restrict__ x,
        const short* __restrict__ Wt, const float* __restrict__ bias,
        short* __restrict__ Qo, short* __restrict__ Ko, short* __restrict__ Vto) {
    __shared__ short lA[2][32 * 64];    //  4 KB per buf (32 rows x 128 B)
    __shared__ short lB[2][96 * 64];    // 12 KB per buf (96 rows x 128 B)

    const int tid  = threadIdx.x;
    const int wid  = tid >> 6;
    const int lane = tid & 63;
    const int l15  = lane & 15;
    const int lg   = lane >> 4;
    const int cb   = blockIdx.x >> 9;        // col-block 0..1
    const int row0 = (blockIdx.x & 511) * 32;
    const int n0   = cb * 96;                // first output col of this block
    const int wr   = wid >> 1;               // 0..1: row half
    const int wc   = wid & 1;                // 0..1: col half

    const int sar = tid >> 4;   // 0..15: row-in-group for A staging
    const int sac = tid & 15;   // 16B chunk within 64-float k-window
    const int bn  = tid >> 3;   // 0..31: B row within round
    const int bc  = tid & 7;    // 16B chunk within 128-B B row

    f32x4 areg[2];

    auto loadA = [&](int k0) {
#pragma unroll
        for (int p = 0; p < 2; ++p) {
            int r = p * 16 + sar;
            areg[p] = *(const f32x4*)(x + (size_t)(row0 + r) * DEMB + k0 + sac * 4);
        }
    };
    auto writeA = [&](int bb) {
        char* base = (char*)lA[bb];
#pragma unroll
        for (int p = 0; p < 2; ++p) {
            int r = p * 16 + sar;
            int byte = r * 128 + ((sac * 8) ^ ((r & 7) << 4));
            s16x4 v;
            v[0] = f2b(areg[p][0]); v[1] = f2b(areg[p][1]);
            v[2] = f2b(areg[p][2]); v[3] = f2b(areg[p][3]);
            *(s16x4*)(base + byte) = v;
        }
    };
    auto stageB = [&](int k0, int bb) {
        const char* wb = (const char*)Wt;
#pragma unroll
        for (int j = 0; j < 3; ++j) {
            int nl = j * 32 + bn;            // local B row 0..95
            const char* src = wb + (size_t)(n0 + nl) * 2048 + k0 * 2
                              + ((bc * 16) ^ ((nl & 7) << 4));
            short* dst = lB[bb] + (size_t)(j * 2048 + wid * 512); // + lane*16B by HW
            gload_lds16(src, dst);
        }
    };

    f32x4 acc[3];
#pragma unroll
    for (int i = 0; i < 3; ++i) acc[i] = (f32x4){0.f, 0.f, 0.f, 0.f};

    loadA(0);
    stageB(0, 0);
    writeA(0);
    __syncthreads();

    int buf = 0;
    for (int ks = 0; ks < 16; ++ks) {
        if (ks < 15) { loadA((ks + 1) * 64); stageB((ks + 1) * 64, buf ^ 1); }

        const char* aB = (const char*)lA[buf];
        const char* bB = (const char*)lB[buf];
        const int ar = wr * 16 + l15;
        const int as = (ar & 7) << 4;
        bf16x8 a0 = *(const bf16x8*)(aB + ar * 128 + ((lg * 16) ^ as));
        bf16x8 a1 = *(const bf16x8*)(aB + ar * 128 + ((lg * 16 + 64) ^ as));
#pragma unroll
        for (int i = 0; i < 3; ++i) {
            int br = wc * 48 + i * 16 + l15;   // local B row 0..95
            int bs = (br & 7) << 4;
            bf16x8 b0 = *(const bf16x8*)(bB + br * 128 + ((lg * 16) ^ bs));
            bf16x8 b1 = *(const bf16x8*)(bB + br * 128 + ((lg * 16 + 64) ^ bs));
            acc[i] = __builtin_amdgcn_mfma_f32_16x16x32_bf16(a0, b0, acc[i], 0, 0, 0);
            acc[i] = __builtin_amdgcn_mfma_f32_16x16x32_bf16(a1, b1, acc[i], 0, 0, 0);
        }

        if (ks < 15) writeA(buf ^ 1);
        __syncthreads();
        buf ^= 1;
    }

    // Epilogue: +bias, write bf16. C/D layout: col = l15, row = lg*4 + j.
    const int t0 = row0 + wr * 16;
#pragma unroll
    for (int i = 0; i < 3; ++i) {
        int n = n0 + wc * 48 + i * 16 + l15;
        float bv_ = bias[n];
#pragma unroll
        for (int j = 0; j < 4; ++j) {
            int t = t0 + lg * 4 + j;
            short v = f2b(acc[i][j] + bv_);
            if (n < 64) {
                Qo[(size_t)t * HD + n] = v;
            } else if (n < 128) {
                Ko[(size_t)t * HD + (n - 64)] = v;
            } else {
                int b = t >> 11, tt = t & 2047, d = n - 128;
                Vto[((size_t)b * HD + d) * SEQ + tt] = v;
            }
        }
    }
}

// ---------------------------------------------------------------------------
// Kernel 2: causal flash attention — r17: r14 KVBLK=64 body (r16's KVBLK=128
//   reverted: neutral-to-negative), UNPAIRED grid for 4 blocks/CU residency.
//   Grid: 8 b x 32 g x 4 split = 1024 blocks x 4 waves. LDS 40960 B divides
//   160KB exactly 4x -> 4 blocks/CU (r12-r15's pairing halved the grid to
//   2 blocks/CU; that was the occupancy limiter). Imbalance handled by
//   longest-job-first: g = 31 - gidx so 8-tile blocks dispatch first and
//   short blocks backfill. Swapped QK^T (lane owns one q-row), in-lane
//   reduce, scalar online state, P packed via 4x ds_write_b64 (swizzled).
// ---------------------------------------------------------------------------
__global__ __launch_bounds__(256, 4) void attn_kernel(const short* __restrict__ Q,
        const short* __restrict__ K, const short* __restrict__ Vt,
        float* __restrict__ Opart, float* __restrict__ mlbuf) {
    __shared__ short lK[2][64 * 64];    // 8 KB per buf
    __shared__ short lV[2][64 * 64];    // 8 KB per buf
    __shared__ short plds[4][16][64];   // per-wave P (row=q, col=kv), swizzled

    const int tid  = threadIdx.x;
    const int wid  = tid >> 6;
    const int lane = tid & 63;
    const int l15  = lane & 15;
    const int lg   = lane >> 4;

    const int split = blockIdx.x & 3;
    const int gidx  = (blockIdx.x >> 2) & 31;
    const int b     = blockIdx.x >> 7;
    const int g     = 31 - gidx;            // LJF: biggest chunks first

    const short* kbb = K  + (size_t)b * SEQ * HD;
    const short* vbb = Vt + (size_t)b * HD * SEQ;

    // staging lane decomposition: 8 rows x 8 chunks(16B) per issue
    const int srow = lane >> 3;
    const int schk = lane & 7;

    auto stageKV = [&](int kv0, int bb) {
#pragma unroll
        for (int i = 0; i < 2; ++i) {
            int rbase = wid * 16 + i * 8;
            int row   = rbase + srow;
            int swz   = (schk * 16) ^ ((row & 7) << 4);
            const char* ksrc = (const char*)(kbb + (size_t)(kv0 + row) * HD) + swz;
            const char* vsrc = (const char*)(vbb + (size_t)row * SEQ + kv0) + swz;
            gload_lds16(ksrc, &lK[bb][rbase * 64]);
            gload_lds16(vsrc, &lV[bb][rbase * 64]);
        }
    };

    const float SC = 0.18033688f;   // 0.125 * log2(e): softmax in base-2 domain
    char* pw = (char*)&plds[wid][0][0];
    const int sw = (l15 & 7) << 4;  // this lane's P-row swizzle

    const int q0    = g * 64 + wid * 16;   // this wave's first q row
    const int ntile = g + 1;               // 64-wide kv tiles for this chunk
    const int qr    = q0 + l15;            // this lane's q row

    // Q fragments
    const short* qbase = Q + ((size_t)(b * SEQ + qr)) * HD + lg * 8;
    bf16x8 qf0 = *(const bf16x8*)(qbase);
    bf16x8 qf1 = *(const bf16x8*)(qbase + 32);

    f32x4 o[4];   // o[df][j] = O[q=l15][d = df*16 + lg*4 + j]
    float m = -1e30f, lsum = 0.f;
#pragma unroll
    for (int df = 0; df < 4; ++df) o[df] = (f32x4){0.f, 0.f, 0.f, 0.f};

    int t = split;
    if (t < ntile) stageKV(t * 64, 0);
    __syncthreads();   // vmcnt(0) drained before barrier => staging visible

    int buf = 0;
    for (; t < ntile; t += NSPL) {
        if (t + NSPL < ntile) stageKV((t + NSPL) * 64, buf ^ 1);

        const int kv0 = t * 64;
        const char* kB = (const char*)lK[buf];
        const char* vB = (const char*)lV[buf];

        // ---- S^T = K Q^T: s[nf] holds col=q(l15), row=kv(nf*16+lg*4+j) ----
        f32x4 s[4];
#pragma unroll
        for (int nf = 0; nf < 4; ++nf) s[nf] = (f32x4){0.f, 0.f, 0.f, 0.f};
#pragma unroll
        for (int nf = 0; nf < 4; ++nf) {
            int br = nf * 16 + l15;
            int bs = (br & 7) << 4;
            bf16x8 kf0 = *(const bf16x8*)(kB + br * 128 + ((lg * 16) ^ bs));
            bf16x8 kf1 = *(const bf16x8*)(kB + br * 128 + ((lg * 16 + 64) ^ bs));
            s[nf] = __builtin_amdgcn_mfma_f32_16x16x32_bf16(kf0, qf0, s[nf], 0, 0, 0);
            s[nf] = __builtin_amdgcn_mfma_f32_16x16x32_bf16(kf1, qf1, s[nf], 0, 0, 0);
        }

        // ---- scale; mask only on the diagonal tile ----
        float sv[4][4];
        if (t == g) {
#pragma unroll
            for (int nf = 0; nf < 4; ++nf)
#pragma unroll
                for (int j = 0; j < 4; ++j) {
                    int kv = kv0 + nf * 16 + lg * 4 + j;
                    float v = s[nf][j] * SC;
                    sv[nf][j] = (kv <= qr) ? v : -1e30f;
                }
        } else {
#pragma unroll
            for (int nf = 0; nf < 4; ++nf)
#pragma unroll
                for (int j = 0; j < 4; ++j) sv[nf][j] = s[nf][j] * SC;
        }

        // ---- row max: 15 in-lane + 2 cross-lg shuffles ----
        float m4[4];
#pragma unroll
        for (int nf = 0; nf < 4; ++nf)
            m4[nf] = fmaxf(fmaxf(sv[nf][0], sv[nf][1]), fmaxf(sv[nf][2], sv[nf][3]));
        float mt = fmaxf(fmaxf(m4[0], m4[1]), fmaxf(m4[2], m4[3]));
        mt = fmaxf(mt, __shfl_xor(mt, 16));
        mt = fmaxf(mt, __shfl_xor(mt, 32));

        // ---- online update (exp2 domain, scalar state) ----
        float mn = fmaxf(fmaxf(m, mt), -1e20f);
        float sf = exp2f(m - mn);
        m = mn;
        lsum *= sf;
#pragma unroll
        for (int df = 0; df < 4; ++df) o[df] *= sf;

        float p[4][4], rsum = 0.f;
#pragma unroll
        for (int nf = 0; nf < 4; ++nf) {
            float r4 = 0.f;
#pragma unroll
            for (int j = 0; j < 4; ++j) {
                p[nf][j] = exp2f(sv[nf][j] - mn);
                r4 += p[nf][j];
            }
            rsum += r4;
        }
        rsum += __shfl_xor(rsum, 16);
        rsum += __shfl_xor(rsum, 32);
        lsum += rsum;

        // ---- pack P (own q-row) into LDS: 4x ds_write_b64, swizzled ----
#pragma unroll
        for (int nf = 0; nf < 4; ++nf) {
            s16x4 pv;
            pv[0] = f2bn(p[nf][0]); pv[1] = f2bn(p[nf][1]);
            pv[2] = f2bn(p[nf][2]); pv[3] = f2bn(p[nf][3]);
            int off = (nf * 16 + lg * 4) * 2;
            *(s16x4*)(pw + l15 * 128 + (off ^ sw)) = pv;
        }

        bf16x8 pa0 = *(const bf16x8*)(pw + l15 * 128 + ((lg * 16) ^ sw));
        bf16x8 pa1 = *(const bf16x8*)(pw + l15 * 128 + ((lg * 16 + 64) ^ sw));

        // ---- O^T += V^T P^T (4 d-frags x 2 k-halves) ----
#pragma unroll
        for (int df = 0; df < 4; ++df) {
            int dr = df * 16 + l15;
            int ds = (dr & 7) << 4;
            bf16x8 vf0 = *(const bf16x8*)(vB + dr * 128 + ((lg * 16) ^ ds));
            bf16x8 vf1 = *(const bf16x8*)(vB + dr * 128 + ((lg * 16 + 64) ^ ds));
            o[df] = __builtin_amdgcn_mfma_f32_16x16x32_bf16(vf0, pa0, o[df], 0, 0, 0);
            o[df] = __builtin_amdgcn_mfma_f32_16x16x32_bf16(vf1, pa1, o[df], 0, 0, 0);
        }

        __syncthreads();   // all waves done with buf; next staging completed
        buf ^= 1;
    }

    // ---- epilogue: unnormalized partials; lane owns q-row qr ----
    {
        size_t R = (size_t)b * SEQ + qr;
        float* op = Opart + ((size_t)split * NROWS + R) * HD;
#pragma unroll
        for (int df = 0; df < 4; ++df)
            *(f32x4*)(op + df * 16 + lg * 4) = o[df];
        if (lg == 0) {
            mlbuf[((size_t)split * NROWS + R) * 2 + 0] = m;
            mlbuf[((size_t)split * NROWS + R) * 2 + 1] = lsum;
        }
    }
}

// ---------------------------------------------------------------------------
// Kernel 3: merge 4 KV-split partials -> normalized output (exp2 domain).
// ---------------------------------------------------------------------------
__global__ __launch_bounds__(256) void merge_kernel(const float* __restrict__ Opart,
        const float* __restrict__ mlbuf, float* __restrict__ out) {
    int tg = blockIdx.x * 256 + threadIdx.x;   // 0 .. 262143
    int rr = tg >> 4;
    int fc = tg & 15;

    float mv[NSPL], lv[NSPL];
    float M = -3e38f;
#pragma unroll
    for (int i = 0; i < NSPL; ++i) {
        mv[i] = mlbuf[((size_t)i * NROWS + rr) * 2 + 0];
        lv[i] = mlbuf[((size_t)i * NROWS + rr) * 2 + 1];
        M = fmaxf(M, mv[i]);
    }
    float L = 0.f;
    f32x4 acc = (f32x4){0.f, 0.f, 0.f, 0.f};
#pragma unroll
    for (int i = 0; i < NSPL; ++i) {
        float w = exp2f(mv[i] - M);
        L += lv[i] * w;
        f32x4 v = *(const f32x4*)(Opart + ((size_t)i * NROWS + rr) * HD + fc * 4);
        acc += v * w;
    }
    f32x4 r = acc / L;
    *(f32x4*)(out + (size_t)rr * HD + fc * 4) = r;
}

// ---------------------------------------------------------------------------
extern "C" void kernel_launch(void* const* d_in, const int* in_sizes, int n_in,
                              void* d_out, int out_size, void* d_ws, size_t ws_size,
                              hipStream_t stream) {
    const float* x  = (const float*)d_in[0];
    const float* Wq = (const float*)d_in[1];
    const float* bq = (const float*)d_in[2];
    const float* Wk = (const float*)d_in[3];
    const float* bk = (const float*)d_in[4];
    const float* Wv = (const float*)d_in[5];
    const float* bv = (const float*)d_in[6];
    float* out = (float*)d_out;

    char* ws = (char*)d_ws;
    // Workspace layout (bytes):
    //   Wt    bf16 [192][1024]        @ 0         (393216)
    //   bias  f32  [192]              @ 393216    (768, pad to 394240)
    //   Q     bf16 [16384][64]        @ 394240    (2097152)
    //   K     bf16 [16384][64]        @ 2491392   (2097152)
    //   Vt    bf16 [8][64][2048]      @ 4588544   (2097152)
    //   Opart f32  [4][16384][64]     @ 6685696   (16777216)
    //   ml    f32  [4][16384][2]      @ 23462912  (524288)   end 23987200
    short* Wt   = (short*)(ws);
    float* bias = (float*)(ws + 393216);
    short* Qb   = (short*)(ws + 394240);
    short* Kb   = (short*)(ws + 394240 + 2097152);
    short* Vtb  = (short*)(ws + 394240 + 2 * 2097152);
    float* Op   = (float*)(ws + 6685696);
    float* ml   = (float*)(ws + 23462912);

    hipLaunchKernelGGL(prep_kernel, dim3(768), dim3(256), 0, stream,
                       Wq, bq, Wk, bk, Wv, bv, Wt, bias);
    hipLaunchKernelGGL(proj_kernel, dim3(1024), dim3(256), 0, stream,
                       x, Wt, bias, Qb, Kb, Vtb);
    hipLaunchKernelGGL(attn_kernel, dim3(1024), dim3(256), 0, stream,
                       Qb, Kb, Vtb, Op, ml);
    hipLaunchKernelGGL(merge_kernel, dim3(1024), dim3(256), 0, stream,
                       Op, ml, out);
}

// Round 19
// 51.529 us; speedup vs baseline: 1.0952x; 1.0952x over previous
//
#include <hip/hip_runtime.h>
#include <hip/hip_bf16.h>
#include <stdint.h>

// Problem constants
#define BATCH 8
#define SEQ   2048
#define DEMB  1024
#define HD    64
#define NROWS (BATCH * SEQ)   // 16384
#define NSPL  4               // KV split factor

typedef __attribute__((ext_vector_type(8))) short bf16x8;  // 8 bf16 in 4 VGPRs
typedef __attribute__((ext_vector_type(4))) short s16x4;   // 4 bf16 (8 B)
typedef __attribute__((ext_vector_type(4))) float f32x4;

// fp32 -> bf16 round-to-nearest-even (bit pattern as short)
__device__ inline short f2b(float f) {
    unsigned u = __builtin_bit_cast(unsigned, f);
    unsigned r = (u + 0x7fffu + ((u >> 16) & 1u)) >> 16;
    return (short)r;
}
// native cast path (compiler can fuse pairs into v_cvt_pk_bf16_f32)
__device__ inline short f2bn(float f) {
    __hip_bfloat16 h(f);
    return __builtin_bit_cast(short, h);
}

// async global->LDS, 16 B per lane; dest = lds_base (wave-uniform) + lane*16
__device__ inline void gload_lds16(const void* g, void* l) {
    auto gp = reinterpret_cast<const __attribute__((address_space(1))) void*>(
        reinterpret_cast<uintptr_t>(g));
    auto lp = reinterpret_cast<__attribute__((address_space(3))) void*>(
        reinterpret_cast<uintptr_t>(l));
    __builtin_amdgcn_global_load_lds(gp, lp, 16, 0, 0);
}

// ---------------------------------------------------------------------------
// Kernel 0: prep — Wt[n][d] = W(d,n) as bf16; bias[192] fp32 concat
// ---------------------------------------------------------------------------
__global__ void prep_kernel(const float* __restrict__ Wq, const float* __restrict__ bq,
                            const float* __restrict__ Wk, const float* __restrict__ bk,
                            const float* __restrict__ Wv, const float* __restrict__ bv,
                            short* __restrict__ Wt, float* __restrict__ bias) {
    int idx = blockIdx.x * blockDim.x + threadIdx.x;   // 0 .. 192*1024-1
    if (idx < 192 * 1024) {
        int n = idx >> 10;
        int d = idx & 1023;
        const float* W = (n < 64) ? Wq : (n < 128) ? Wk : Wv;
        int nn = n & 63;
        Wt[idx] = f2b(W[(size_t)d * 64 + nn]);
    }
    if (idx < 192) {
        const float* bb = (idx < 64) ? bq : (idx < 128) ? bk : bv;
        bias[idx] = bb[idx & 63];
    }
}

// ---------------------------------------------------------------------------
// Kernel 1: QKV projection — r15 N-split version (passing, unchanged).
//   BM=32, BN=96, grid 1024 (bid = c*512 + r), LDS 32KB -> 4 blocks/CU.
// ---------------------------------------------------------------------------
__global__ __launch_bounds__(256) void proj_kernel(const float* __restrict__ x,
        const short* __restrict__ Wt, const float* __restrict__ bias,
        short* __restrict__ Qo, short* __restrict__ Ko, short* __restrict__ Vto) {
    __shared__ short lA[2][32 * 64];    //  4 KB per buf (32 rows x 128 B)
    __shared__ short lB[2][96 * 64];    // 12 KB per buf (96 rows x 128 B)

    const int tid  = threadIdx.x;
    const int wid  = tid >> 6;
    const int lane = tid & 63;
    const int l15  = lane & 15;
    const int lg   = lane >> 4;
    const int cb   = blockIdx.x >> 9;        // col-block 0..1
    const int row0 = (blockIdx.x & 511) * 32;
    const int n0   = cb * 96;                // first output col of this block
    const int wr   = wid >> 1;               // 0..1: row half
    const int wc   = wid & 1;                // 0..1: col half

    const int sar = tid >> 4;   // 0..15: row-in-group for A staging
    const int sac = tid & 15;   // 16B chunk within 64-float k-window
    const int bn  = tid >> 3;   // 0..31: B row within round
    const int bc  = tid & 7;    // 16B chunk within 128-B B row

    f32x4 areg[2];

    auto loadA = [&](int k0) {
#pragma unroll
        for (int p = 0; p < 2; ++p) {
            int r = p * 16 + sar;
            areg[p] = *(const f32x4*)(x + (size_t)(row0 + r) * DEMB + k0 + sac * 4);
        }
    };
    auto writeA = [&](int bb) {
        char* base = (char*)lA[bb];
#pragma unroll
        for (int p = 0; p < 2; ++p) {
            int r = p * 16 + sar;
            int byte = r * 128 + ((sac * 8) ^ ((r & 7) << 4));
            s16x4 v;
            v[0] = f2b(areg[p][0]); v[1] = f2b(areg[p][1]);
            v[2] = f2b(areg[p][2]); v[3] = f2b(areg[p][3]);
            *(s16x4*)(base + byte) = v;
        }
    };
    auto stageB = [&](int k0, int bb) {
        const char* wb = (const char*)Wt;
#pragma unroll
        for (int j = 0; j < 3; ++j) {
            int nl = j * 32 + bn;            // local B row 0..95
            const char* src = wb + (size_t)(n0 + nl) * 2048 + k0 * 2
                              + ((bc * 16) ^ ((nl & 7) << 4));
            short* dst = lB[bb] + (size_t)(j * 2048 + wid * 512); // + lane*16B by HW
            gload_lds16(src, dst);
        }
    };

    f32x4 acc[3];
#pragma unroll
    for (int i = 0; i < 3; ++i) acc[i] = (f32x4){0.f, 0.f, 0.f, 0.f};

    loadA(0);
    stageB(0, 0);
    writeA(0);
    __syncthreads();

    int buf = 0;
    for (int ks = 0; ks < 16; ++ks) {
        if (ks < 15) { loadA((ks + 1) * 64); stageB((ks + 1) * 64, buf ^ 1); }

        const char* aB = (const char*)lA[buf];
        const char* bB = (const char*)lB[buf];
        const int ar = wr * 16 + l15;
        const int as = (ar & 7) << 4;
        bf16x8 a0 = *(const bf16x8*)(aB + ar * 128 + ((lg * 16) ^ as));
        bf16x8 a1 = *(const bf16x8*)(aB + ar * 128 + ((lg * 16 + 64) ^ as));
#pragma unroll
        for (int i = 0; i < 3; ++i) {
            int br = wc * 48 + i * 16 + l15;   // local B row 0..95
            int bs = (br & 7) << 4;
            bf16x8 b0 = *(const bf16x8*)(bB + br * 128 + ((lg * 16) ^ bs));
            bf16x8 b1 = *(const bf16x8*)(bB + br * 128 + ((lg * 16 + 64) ^ bs));
            acc[i] = __builtin_amdgcn_mfma_f32_16x16x32_bf16(a0, b0, acc[i], 0, 0, 0);
            acc[i] = __builtin_amdgcn_mfma_f32_16x16x32_bf16(a1, b1, acc[i], 0, 0, 0);
        }

        if (ks < 15) writeA(buf ^ 1);
        __syncthreads();
        buf ^= 1;
    }

    // Epilogue: +bias, write bf16. C/D layout: col = l15, row = lg*4 + j.
    const int t0 = row0 + wr * 16;
#pragma unroll
    for (int i = 0; i < 3; ++i) {
        int n = n0 + wc * 48 + i * 16 + l15;
        float bv_ = bias[n];
#pragma unroll
        for (int j = 0; j < 4; ++j) {
            int t = t0 + lg * 4 + j;
            short v = f2b(acc[i][j] + bv_);
            if (n < 64) {
                Qo[(size_t)t * HD + n] = v;
            } else if (n < 128) {
                Ko[(size_t)t * HD + (n - 64)] = v;
            } else {
                int b = t >> 11, tt = t & 2047, d = n - 128;
                Vto[((size_t)b * HD + d) * SEQ + tt] = v;
            }
        }
    }
}

// ---------------------------------------------------------------------------
// Kernel 2: causal flash attention — r18: exact r15 structure (best measured:
//   paired chunks g=pr / 31-pr, KVBLK=64, NSPL=4, 512 blocks x 4 waves,
//   swapped QK^T with per-lane q-row) + T13 DEFERRED RESCALE: when
//   __all(mt <= m + 8) keep m_old and skip the O/lsum rescale (P bounded by
//   2^8, safe in bf16; saves rescale VALU on most tiles). r16 (KVBLK=128)
//   and r17 (unpaired 4 blocks/CU) both measured worse and are reverted.
// ---------------------------------------------------------------------------
__global__ __launch_bounds__(256, 4) void attn_kernel(const short* __restrict__ Q,
        const short* __restrict__ K, const short* __restrict__ Vt,
        float* __restrict__ Opart, float* __restrict__ mlbuf) {
    __shared__ short lK[2][64 * 64];    // 8 KB per buf
    __shared__ short lV[2][64 * 64];    // 8 KB per buf
    __shared__ short plds[4][16][64];   // per-wave P (row=q, col=kv), swizzled

    const int tid  = threadIdx.x;
    const int wid  = tid >> 6;
    const int lane = tid & 63;
    const int l15  = lane & 15;
    const int lg   = lane >> 4;

    const int split = blockIdx.x & 3;
    const int pr    = (blockIdx.x >> 2) & 15;
    const int b     = blockIdx.x >> 6;

    const short* kbb = K  + (size_t)b * SEQ * HD;
    const short* vbb = Vt + (size_t)b * HD * SEQ;

    // staging lane decomposition: 8 rows x 8 chunks(16B) per issue
    const int srow = lane >> 3;
    const int schk = lane & 7;

    auto stageKV = [&](int kv0, int bb) {
#pragma unroll
        for (int i = 0; i < 2; ++i) {
            int rbase = wid * 16 + i * 8;
            int row   = rbase + srow;
            int swz   = (schk * 16) ^ ((row & 7) << 4);
            const char* ksrc = (const char*)(kbb + (size_t)(kv0 + row) * HD) + swz;
            const char* vsrc = (const char*)(vbb + (size_t)row * SEQ + kv0) + swz;
            gload_lds16(ksrc, &lK[bb][rbase * 64]);
            gload_lds16(vsrc, &lV[bb][rbase * 64]);
        }
    };

    const float SC = 0.18033688f;   // 0.125 * log2(e): softmax in base-2 domain
    char* pw = (char*)&plds[wid][0][0];
    const int sw = (l15 & 7) << 4;  // this lane's P-row swizzle

    for (int ci = 0; ci < 2; ++ci) {
        const int g     = ci ? (31 - pr) : pr;
        const int q0    = g * 64 + wid * 16;   // this wave's first q row
        const int ntile = g + 1;               // 64-wide kv tiles for this chunk
        const int qr    = q0 + l15;            // this lane's q row

        // Q fragments for this chunk
        const short* qbase = Q + ((size_t)(b * SEQ + qr)) * HD + lg * 8;
        bf16x8 qf0 = *(const bf16x8*)(qbase);
        bf16x8 qf1 = *(const bf16x8*)(qbase + 32);

        f32x4 o[4];   // o[df][j] = O[q=l15][d = df*16 + lg*4 + j]
        float m = -1e30f, lsum = 0.f;
#pragma unroll
        for (int df = 0; df < 4; ++df) o[df] = (f32x4){0.f, 0.f, 0.f, 0.f};

        int t = split;
        if (t < ntile) stageKV(t * 64, 0);
        __syncthreads();   // vmcnt(0) drained before barrier => staging visible

        int buf = 0;
        for (; t < ntile; t += NSPL) {
            if (t + NSPL < ntile) stageKV((t + NSPL) * 64, buf ^ 1);

            const int kv0 = t * 64;
            const char* kB = (const char*)lK[buf];
            const char* vB = (const char*)lV[buf];

            // ---- S^T = K Q^T: s[nf] holds col=q(l15), row=kv(nf*16+lg*4+j) ----
            f32x4 s[4];
#pragma unroll
            for (int nf = 0; nf < 4; ++nf) s[nf] = (f32x4){0.f, 0.f, 0.f, 0.f};
#pragma unroll
            for (int nf = 0; nf < 4; ++nf) {
                int br = nf * 16 + l15;
                int bs = (br & 7) << 4;
                bf16x8 kf0 = *(const bf16x8*)(kB + br * 128 + ((lg * 16) ^ bs));
                bf16x8 kf1 = *(const bf16x8*)(kB + br * 128 + ((lg * 16 + 64) ^ bs));
                s[nf] = __builtin_amdgcn_mfma_f32_16x16x32_bf16(kf0, qf0, s[nf], 0, 0, 0);
                s[nf] = __builtin_amdgcn_mfma_f32_16x16x32_bf16(kf1, qf1, s[nf], 0, 0, 0);
            }

            // ---- scale; mask only on the diagonal tile ----
            float sv[4][4];
            if (t == g) {
#pragma unroll
                for (int nf = 0; nf < 4; ++nf)
#pragma unroll
                    for (int j = 0; j < 4; ++j) {
                        int kv = kv0 + nf * 16 + lg * 4 + j;
                        float v = s[nf][j] * SC;
                        sv[nf][j] = (kv <= qr) ? v : -1e30f;
                    }
            } else {
#pragma unroll
                for (int nf = 0; nf < 4; ++nf)
#pragma unroll
                    for (int j = 0; j < 4; ++j) sv[nf][j] = s[nf][j] * SC;
            }

            // ---- row max: 15 in-lane + 2 cross-lg shuffles ----
            float m4[4];
#pragma unroll
            for (int nf = 0; nf < 4; ++nf)
                m4[nf] = fmaxf(fmaxf(sv[nf][0], sv[nf][1]), fmaxf(sv[nf][2], sv[nf][3]));
            float mt = fmaxf(fmaxf(m4[0], m4[1]), fmaxf(m4[2], m4[3]));
            mt = fmaxf(mt, __shfl_xor(mt, 16));
            mt = fmaxf(mt, __shfl_xor(mt, 32));

            // ---- online update (exp2 domain) with T13 deferred rescale ----
            // Skip the O/lsum rescale when no lane's tile-max exceeds the
            // running max by >8: P is then bounded by 2^8, safe for bf16.
            if (!__all(mt <= m + 8.0f)) {
                float mn = fmaxf(fmaxf(m, mt), -1e20f);
                float sf = exp2f(m - mn);
                m = mn;
                lsum *= sf;
#pragma unroll
                for (int df = 0; df < 4; ++df) o[df] *= sf;
            }

            float p[4][4], rsum = 0.f;
#pragma unroll
            for (int nf = 0; nf < 4; ++nf) {
                float r4 = 0.f;
#pragma unroll
                for (int j = 0; j < 4; ++j) {
                    p[nf][j] = exp2f(sv[nf][j] - m);
                    r4 += p[nf][j];
                }
                rsum += r4;
            }
            rsum += __shfl_xor(rsum, 16);
            rsum += __shfl_xor(rsum, 32);
            lsum += rsum;

            // ---- pack P (own q-row) into LDS: 4x ds_write_b64, swizzled ----
#pragma unroll
            for (int nf = 0; nf < 4; ++nf) {
                s16x4 pv;
                pv[0] = f2bn(p[nf][0]); pv[1] = f2bn(p[nf][1]);
                pv[2] = f2bn(p[nf][2]); pv[3] = f2bn(p[nf][3]);
                int off = (nf * 16 + lg * 4) * 2;
                *(s16x4*)(pw + l15 * 128 + (off ^ sw)) = pv;
            }

            bf16x8 pa0 = *(const bf16x8*)(pw + l15 * 128 + ((lg * 16) ^ sw));
            bf16x8 pa1 = *(const bf16x8*)(pw + l15 * 128 + ((lg * 16 + 64) ^ sw));

            // ---- O^T += V^T P^T (4 d-frags x 2 k-halves) ----
#pragma unroll
            for (int df = 0; df < 4; ++df) {
                int dr = df * 16 + l15;
                int ds = (dr & 7) << 4;
                bf16x8 vf0 = *(const bf16x8*)(vB + dr * 128 + ((lg * 16) ^ ds));
                bf16x8 vf1 = *(const bf16x8*)(vB + dr * 128 + ((lg * 16 + 64) ^ ds));
                o[df] = __builtin_amdgcn_mfma_f32_16x16x32_bf16(vf0, pa0, o[df], 0, 0, 0);
                o[df] = __builtin_amdgcn_mfma_f32_16x16x32_bf16(vf1, pa1, o[df], 0, 0, 0);
            }

            __syncthreads();   // all waves done with buf; next staging completed
            buf ^= 1;
        }

        // ---- epilogue: unnormalized partials; lane owns q-row qr ----
        {
            size_t R = (size_t)b * SEQ + qr;
            float* op = Opart + ((size_t)split * NROWS + R) * HD;
#pragma unroll
            for (int df = 0; df < 4; ++df)
                *(f32x4*)(op + df * 16 + lg * 4) = o[df];
            if (lg == 0) {
                mlbuf[((size_t)split * NROWS + R) * 2 + 0] = m;
                mlbuf[((size_t)split * NROWS + R) * 2 + 1] = lsum;
            }
        }
    }
}

// ---------------------------------------------------------------------------
// Kernel 3: merge 4 KV-split partials -> normalized output (exp2 domain).
// ---------------------------------------------------------------------------
__global__ __launch_bounds__(256) void merge_kernel(const float* __restrict__ Opart,
        const float* __restrict__ mlbuf, float* __restrict__ out) {
    int tg = blockIdx.x * 256 + threadIdx.x;   // 0 .. 262143
    int rr = tg >> 4;
    int fc = tg & 15;

    float mv[NSPL], lv[NSPL];
    float M = -3e38f;
#pragma unroll
    for (int i = 0; i < NSPL; ++i) {
        mv[i] = mlbuf[((size_t)i * NROWS + rr) * 2 + 0];
        lv[i] = mlbuf[((size_t)i * NROWS + rr) * 2 + 1];
        M = fmaxf(M, mv[i]);
    }
    float L = 0.f;
    f32x4 acc = (f32x4){0.f, 0.f, 0.f, 0.f};
#pragma unroll
    for (int i = 0; i < NSPL; ++i) {
        float w = exp2f(mv[i] - M);
        L += lv[i] * w;
        f32x4 v = *(const f32x4*)(Opart + ((size_t)i * NROWS + rr) * HD + fc * 4);
        acc += v * w;
    }
    f32x4 r = acc / L;
    *(f32x4*)(out + (size_t)rr * HD + fc * 4) = r;
}

// ---------------------------------------------------------------------------
extern "C" void kernel_launch(void* const* d_in, const int* in_sizes, int n_in,
                              void* d_out, int out_size, void* d_ws, size_t ws_size,
                              hipStream_t stream) {
    const float* x  = (const float*)d_in[0];
    const float* Wq = (const float*)d_in[1];
    const float* bq = (const float*)d_in[2];
    const float* Wk = (const float*)d_in[3];
    const float* bk = (const float*)d_in[4];
    const float* Wv = (const float*)d_in[5];
    const float* bv = (const float*)d_in[6];
    float* out = (float*)d_out;

    char* ws = (char*)d_ws;
    // Workspace layout (bytes):
    //   Wt    bf16 [192][1024]        @ 0         (393216)
    //   bias  f32  [192]              @ 393216    (768, pad to 394240)
    //   Q     bf16 [16384][64]        @ 394240    (2097152)
    //   K     bf16 [16384][64]        @ 2491392   (2097152)
    //   Vt    bf16 [8][64][2048]      @ 4588544   (2097152)
    //   Opart f32  [4][16384][64]     @ 6685696   (16777216)
    //   ml    f32  [4][16384][2]      @ 23462912  (524288)   end 23987200
    short* Wt   = (short*)(ws);
    float* bias = (float*)(ws + 393216);
    short* Qb   = (short*)(ws + 394240);
    short* Kb   = (short*)(ws + 394240 + 2097152);
    short* Vtb  = (short*)(ws + 394240 + 2 * 2097152);
    float* Op   = (float*)(ws + 6685696);
    float* ml   = (float*)(ws + 23462912);

    hipLaunchKernelGGL(prep_kernel, dim3(768), dim3(256), 0, stream,
                       Wq, bq, Wk, bk, Wv, bv, Wt, bias);
    hipLaunchKernelGGL(proj_kernel, dim3(1024), dim3(256), 0, stream,
                       x, Wt, bias, Qb, Kb, Vtb);
    hipLaunchKernelGGL(attn_kernel, dim3(512), dim3(256), 0, stream,
                       Qb, Kb, Vtb, Op, ml);
    hipLaunchKernelGGL(merge_kernel, dim3(1024), dim3(256), 0, stream,
                       Op, ml, out);
}